// Round 1
// baseline (234.377 us; speedup 1.0000x reference)
//
#include <hip/hip_runtime.h>
#include <hip/hip_bf16.h>

// ---------------------------------------------------------------------------
// ClusterGNN fused pipeline for MI355X (gfx950).
// Structure:
//   k_pool     : 4x4x4 mean-pool x_concat (64^3x32) -> x (4096x32)
//   k_order    : stable compaction per cluster (== stable argsort), gather xi
//   k_wcvt     : conv1_w/conv2_w -> bf16
//   k_mlp      : cent -> MLP -> sigmoid sw -> w_eff = gcn_w @ sw
//   k_conv<M>  : fused pair-chain, recomputed 3x:
//                M=0: h1 = d@w1^T, accumulate per-channel sum/sumsq (BN1 stats)
//                M=1: a1 = lrelu(bn1(h1)); h2 = a1@w2^T; BN2 stats
//                M=2: a2 = lrelu(bn2(h2)); logits = a2@w3  (stored)
//   k_bnco     : stats -> (scale, shift) coefficients (conv bias cancels in BN)
//   k_graph    : row softmax (diag excluded) + adj@xi + agg@w_eff + lrelu, BN3 stats
//   k_bn3      : apply BN3, scatter to x_new via order
//   k_final    : overlapping-window gather + residual add -> out
// ---------------------------------------------------------------------------

typedef short bfrag8 __attribute__((ext_vector_type(8)));   // 8 bf16 (4 VGPR)
typedef float f32x4  __attribute__((ext_vector_type(4)));

#define DI __device__ __forceinline__

DI unsigned short f2bf(float f) {
  return __builtin_bit_cast(unsigned short, __float2bfloat16(f));
}
DI float bf2f(unsigned short u) {
  return __builtin_bit_cast(float, ((unsigned)u) << 16);
}

// ------------------------------- pool --------------------------------------
__global__ __launch_bounds__(256) void k_pool(const float* __restrict__ xc,
                                              float* __restrict__ x) {
  int idx = blockIdx.x * 256 + threadIdx.x;      // 131072 = 4096*32
  int c = idx & 31, g = idx >> 5;
  int gz = g & 15, gy = (g >> 4) & 15, gx = g >> 8;
  float s = 0.f;
  for (int ix = 0; ix < 4; ++ix)
    for (int iy = 0; iy < 4; ++iy)
      for (int iz = 0; iz < 4; ++iz) {
        int X = gx * 4 + ix, Y = gy * 4 + iy, Z = gz * 4 + iz;
        s += xc[(size_t)(((X << 6) | Y) << 6 | Z) * 32 + c];
      }
  x[idx] = s * (1.f / 64.f);
}

// --------------------------- order + gather --------------------------------
__global__ __launch_bounds__(256) void k_order(const int* __restrict__ ci,
                                               const float* __restrict__ x,
                                               int* __restrict__ order,
                                               float* __restrict__ xi) {
  const int k = blockIdx.x, t = threadIdx.x;
  __shared__ int scnt[256];
  __shared__ int ordl[256];
  int match[16];
  int cnt = 0;
#pragma unroll
  for (int j = 0; j < 16; ++j) { match[j] = (ci[t * 16 + j] == k); cnt += match[j]; }
  scnt[t] = cnt;
  __syncthreads();
  for (int off = 1; off < 256; off <<= 1) {        // inclusive Hillis-Steele
    int v = (t >= off) ? scnt[t - off] : 0;
    __syncthreads();
    scnt[t] += v;
    __syncthreads();
  }
  int pos = scnt[t] - cnt;                         // exclusive
#pragma unroll
  for (int j = 0; j < 16; ++j)
    if (match[j]) ordl[pos++] = t * 16 + j;
  __syncthreads();
  int src = ordl[t];
  order[k * 256 + t] = src;
  const f32x4* xr = (const f32x4*)(x + (size_t)src * 32);
  f32x4* xo = (f32x4*)(xi + ((size_t)k * 256 + t) * 32);
#pragma unroll
  for (int c = 0; c < 8; ++c) xo[c] = xr[c];
}

// ---------------------------- weight cvt -----------------------------------
__global__ __launch_bounds__(256) void k_wcvt(const float* __restrict__ w1,
                                              const float* __restrict__ w2,
                                              unsigned short* __restrict__ w1b,
                                              unsigned short* __restrict__ w2b) {
  int i = blockIdx.x * 256 + threadIdx.x;
  if (i < 32768) w1b[i] = f2bf(w1[i]);
  if (i < 98304) w2b[i] = f2bf(w2[i]);
}

// ------------------------------- MLP ---------------------------------------
__global__ __launch_bounds__(256) void k_mlp(
    const float* __restrict__ xi,
    const float* __restrict__ mw1, const float* __restrict__ mb1,
    const float* __restrict__ mw2, const float* __restrict__ mb2,
    const float* __restrict__ mw3, const float* __restrict__ mb3,
    const float* __restrict__ gcnw, float* __restrict__ weff) {
  const int k = blockIdx.x, t = threadIdx.x;
  __shared__ float red[256];
  __shared__ float cent[32];
  __shared__ float h1[128];
  __shared__ float h2[256];
  __shared__ float sw[1024];

  const float* xk = xi + (size_t)k * 8192;
  {
    int c = t & 31, rp = t >> 5;
    float ssum = 0.f;
    for (int r = rp; r < 256; r += 8) ssum += xk[r * 32 + c];
    red[t] = ssum;
  }
  __syncthreads();
  if (t < 32) {
    float tot = 0.f;
#pragma unroll
    for (int g = 0; g < 8; ++g) tot += red[g * 32 + t];
    cent[t] = tot * (1.f / 256.f);
  }
  __syncthreads();
  if (t < 128) {
    float s = mb1[t];
#pragma unroll
    for (int c = 0; c < 32; ++c) s += cent[c] * mw1[c * 128 + t];
    h1[t] = fmaxf(s, 0.f);
  }
  __syncthreads();
  {
    float s = mb2[t];
    for (int j = 0; j < 128; ++j) s += h1[j] * mw2[j * 256 + t];
    h2[t] = fmaxf(s, 0.f);
  }
  __syncthreads();
#pragma unroll
  for (int oo = 0; oo < 4; ++oo) {
    int o = oo * 256 + t;
    float s = mb3[o];
    for (int j = 0; j < 256; ++j) s += h2[j] * mw3[j * 1024 + o];
    sw[o] = 1.f / (1.f + __expf(-s));
  }
  __syncthreads();
  const float* gk = gcnw + (size_t)k * 2048;
  float* wo = weff + (size_t)k * 2048;
  for (int e = t; e < 2048; e += 256) {
    int u = e >> 5, v = e & 31;
    float s = 0.f;
#pragma unroll
    for (int ss = 0; ss < 32; ++ss) s += gk[u * 32 + ss] * sw[ss * 32 + v];
    wo[e] = s;
  }
}

// --------------------------- fused pair chain -------------------------------
// Block: 4 waves; per block: fixed (cluster k, q-half of 128), loop over 4 p.
// Per wave: 32 q-rows. GEMM1: d(32x32 k-dim) -> h1(32x64). GEMM2: a1 -> h2(32x96).
template <int MODE>
__global__ __launch_bounds__(256) void k_conv(
    const float* __restrict__ xi,
    const unsigned short* __restrict__ w1b,
    const unsigned short* __restrict__ w2b,
    const float2* __restrict__ coef1,
    const float2* __restrict__ coef2,
    const float* __restrict__ conv3w,
    float* __restrict__ stats1,
    float* __restrict__ stats2,
    float* __restrict__ logits) {
  const int k   = blockIdx.y;
  const int qh  = blockIdx.x & 1;
  const int pg  = blockIdx.x >> 1;       // 0..63
  const int tid = threadIdx.x;
  const int lane = tid & 63;
  const int wv  = tid >> 6;              // wave 0..3
  const int l15 = lane & 15;
  const int lg  = lane >> 4;             // 0..3

  __shared__ __align__(16) float xq[128][36];              // q-rows, +4 pad
  __shared__ __align__(16) unsigned short a1s[4][32 * 72]; // per-wave a1, stride 72
  __shared__ float sred[192];

  const float* xik = xi + (size_t)k * (256 * 32);

  {  // stage the 128 q rows once per block
    const int r = tid >> 1, h = tid & 1;
    const f32x4* s4 = (const f32x4*)(xik + (size_t)(qh * 128 + r) * 32 + h * 16);
    f32x4* d4 = (f32x4*)&xq[r][h * 16];
    d4[0] = s4[0]; d4[1] = s4[1]; d4[2] = s4[2]; d4[3] = s4[3];
  }

  // B fragments (per-lane, from global bf16; small + L2 resident)
  bfrag8 B1[4];
  {
    const unsigned short* w1k = w1b + k * (64 * 32);
#pragma unroll
    for (int f = 0; f < 4; ++f)
      B1[f] = *(const bfrag8*)(w1k + (16 * f + l15) * 32 + lg * 8);
  }
  bfrag8 B2[6][2];
  float2 c1[4];
  float2 c2[6];
  float w3v[6];
  if constexpr (MODE >= 1) {
    const unsigned short* w2k = w2b + k * (96 * 64);
#pragma unroll
    for (int f = 0; f < 6; ++f) {
      B2[f][0] = *(const bfrag8*)(w2k + (16 * f + l15) * 64 + lg * 8);
      B2[f][1] = *(const bfrag8*)(w2k + (16 * f + l15) * 64 + 32 + lg * 8);
    }
#pragma unroll
    for (int f = 0; f < 4; ++f) c1[f] = coef1[k * 64 + 16 * f + l15];
  }
  if constexpr (MODE == 2) {
#pragma unroll
    for (int f = 0; f < 6; ++f) {
      c2[f]  = coef2[k * 96 + 16 * f + l15];
      w3v[f] = conv3w[k * 96 + 16 * f + l15];
    }
  }

  constexpr int NF = (MODE == 0) ? 4 : 6;
  float ssum[6], ssq[6];
#pragma unroll
  for (int f = 0; f < 6; ++f) { ssum[f] = 0.f; ssq[f] = 0.f; }

  __syncthreads();

  for (int it = 0; it < 4; ++it) {
    const int p = pg * 4 + it;
    float pv[8];
    {
      const float* xp = xik + (size_t)p * 32 + lg * 8;
#pragma unroll
      for (int j = 0; j < 8; ++j) pv[j] = xp[j];
    }
#pragma unroll
    for (int rt = 0; rt < 2; ++rt) {
      // A fragment: d = |xi_q - xi_p|, row = lane&15, k = (lane>>4)*8 + j
      const float* qr = &xq[wv * 32 + rt * 16 + l15][lg * 8];
      bfrag8 af;
#pragma unroll
      for (int j = 0; j < 8; ++j) af[j] = (short)f2bf(fabsf(qr[j] - pv[j]));
      const f32x4 z = {0.f, 0.f, 0.f, 0.f};
      f32x4 acc1[4];
#pragma unroll
      for (int f = 0; f < 4; ++f)
        acc1[f] = __builtin_amdgcn_mfma_f32_16x16x32_bf16(af, B1[f], z, 0, 0, 0);
      if constexpr (MODE == 0) {
#pragma unroll
        for (int f = 0; f < 4; ++f)
#pragma unroll
          for (int r = 0; r < 4; ++r) { float h = acc1[f][r]; ssum[f] += h; ssq[f] += h * h; }
      } else {
        // a1 = lrelu(acc*s + T); stash to per-wave LDS (C-layout -> row major)
        unsigned short* aw = &a1s[wv][(rt * 16 + lg * 4) * 72 + l15];
#pragma unroll
        for (int f = 0; f < 4; ++f)
#pragma unroll
          for (int r = 0; r < 4; ++r) {
            float h = acc1[f][r] * c1[f].x + c1[f].y;
            h = fmaxf(h, 0.2f * h);
            aw[r * 72 + 16 * f] = f2bf(h);
          }
      }
    }
    if constexpr (MODE >= 1) {
#pragma unroll
      for (int rt = 0; rt < 2; ++rt) {
        bfrag8 A0 = *(const bfrag8*)&a1s[wv][(rt * 16 + l15) * 72 + lg * 8];
        bfrag8 A1 = *(const bfrag8*)&a1s[wv][(rt * 16 + l15) * 72 + 32 + lg * 8];
        f32x4 acc2[6];
#pragma unroll
        for (int f = 0; f < 6; ++f) {
          f32x4 a = {0.f, 0.f, 0.f, 0.f};
          a = __builtin_amdgcn_mfma_f32_16x16x32_bf16(A0, B2[f][0], a, 0, 0, 0);
          a = __builtin_amdgcn_mfma_f32_16x16x32_bf16(A1, B2[f][1], a, 0, 0, 0);
          acc2[f] = a;
        }
        if constexpr (MODE == 1) {
#pragma unroll
          for (int f = 0; f < 6; ++f)
#pragma unroll
            for (int r = 0; r < 4; ++r) { float h = acc2[f][r]; ssum[f] += h; ssq[f] += h * h; }
        } else {
          f32x4 lp = {0.f, 0.f, 0.f, 0.f};
#pragma unroll
          for (int f = 0; f < 6; ++f)
#pragma unroll
            for (int r = 0; r < 4; ++r) {
              float h = acc2[f][r] * c2[f].x + c2[f].y;
              h = fmaxf(h, 0.2f * h);
              lp[r] += h * w3v[f];
            }
#pragma unroll
          for (int m = 1; m < 16; m <<= 1) {
            lp[0] += __shfl_xor(lp[0], m);
            lp[1] += __shfl_xor(lp[1], m);
            lp[2] += __shfl_xor(lp[2], m);
            lp[3] += __shfl_xor(lp[3], m);
          }
          if (l15 == 0) {
            const int q = qh * 128 + wv * 32 + rt * 16 + lg * 4;
            *(f32x4*)&logits[(size_t)k * 65536 + (size_t)p * 256 + q] = lp;
          }
        }
      }
    }
  }

  if constexpr (MODE <= 1) {
#pragma unroll
    for (int f = 0; f < NF; ++f) {
      ssum[f] += __shfl_xor(ssum[f], 16); ssum[f] += __shfl_xor(ssum[f], 32);
      ssq[f]  += __shfl_xor(ssq[f], 16);  ssq[f]  += __shfl_xor(ssq[f], 32);
    }
    __syncthreads();
    if (tid < 2 * 16 * NF) sred[tid] = 0.f;
    __syncthreads();
    if (lg == 0) {
#pragma unroll
      for (int f = 0; f < NF; ++f) {
        atomicAdd(&sred[(16 * f + l15) * 2 + 0], ssum[f]);
        atomicAdd(&sred[(16 * f + l15) * 2 + 1], ssq[f]);
      }
    }
    __syncthreads();
    float* gs = (MODE == 0) ? stats1 : stats2;
    if (tid < 2 * 16 * NF) atomicAdd(&gs[k * (2 * 16 * NF) + tid], sred[tid]);
  }
}

// ------------------------- BN coefficient kernel ----------------------------
// conv bias cancels inside BN: a = lrelu((acc - mean_acc)*s + beta)
__global__ void k_bnco(const float* __restrict__ stats,
                       const float* __restrict__ g,
                       const float* __restrict__ b,
                       float2* __restrict__ coef, int nch) {
  int i = blockIdx.x * 256 + threadIdx.x;
  if (i >= 16 * nch) return;
  float sum = stats[i * 2], sq = stats[i * 2 + 1];
  const float invN = 1.f / 65536.f;
  float mean = sum * invN;
  float var = sq * invN - mean * mean;
  float s = g[i] * rsqrtf(fmaxf(var, 0.f) + 1e-5f);
  coef[i] = make_float2(s, b[i] - mean * s);
}

// --------------------- softmax + adj@xi + GCN + BN3 stats -------------------
__global__ __launch_bounds__(256) void k_graph(
    const float* __restrict__ xi,
    const float* __restrict__ logits,
    const float* __restrict__ weff,
    float* __restrict__ hi,
    float* __restrict__ stats3) {
  const int k  = blockIdx.y;
  const int pc = blockIdx.x;   // 0..7, 32 rows each
  const int tid = threadIdx.x;
  __shared__ unsigned short xis[256 * 36];   // bf16 xi, pad 36
  __shared__ float es[32][258];
  __shared__ float axs[32][33];
  __shared__ float inv_s[32];
  __shared__ float s3[64];

  const float* xik = xi + (size_t)k * 8192;
  for (int i = tid; i < 8192; i += 256) {
    int r = i >> 5, c = i & 31;
    xis[r * 36 + c] = f2bf(xik[i]);
  }
  if (tid < 64) s3[tid] = 0.f;
  __syncthreads();

  const int row = tid >> 3;    // 0..31
  const int s   = tid & 7;
  const int pglob = pc * 32 + row;
  const float* lrow = logits + (size_t)k * 65536 + (size_t)pglob * 256;

  float m = -1e30f;
  for (int q = s; q < 256; q += 8) {
    float v = lrow[q];
    m = (q == pglob) ? m : fmaxf(m, v);
  }
  m = fmaxf(m, __shfl_xor(m, 1));
  m = fmaxf(m, __shfl_xor(m, 2));
  m = fmaxf(m, __shfl_xor(m, 4));
  float sum = 0.f;
  for (int q = s; q < 256; q += 8) {
    float e = (q == pglob) ? 0.f : __expf(lrow[q] - m);
    es[row][q] = e;
    sum += e;
  }
  sum += __shfl_xor(sum, 1);
  sum += __shfl_xor(sum, 2);
  sum += __shfl_xor(sum, 4);
  if (s == 0) inv_s[row] = 1.f / sum;
  __syncthreads();

  // adjxi = (adj @ xi)[row][c0..c0+4)
  const int c0 = s * 4;
  float a0 = 0.f, a1 = 0.f, a2 = 0.f, a3 = 0.f;
  for (int q = 0; q < 256; ++q) {
    float e = es[row][q];
    const unsigned short* xr = &xis[q * 36 + c0];
    a0 += e * bf2f(xr[0]);
    a1 += e * bf2f(xr[1]);
    a2 += e * bf2f(xr[2]);
    a3 += e * bf2f(xr[3]);
  }
  float iv = inv_s[row];
  axs[row][c0 + 0] = a0 * iv; axs[row][c0 + 1] = a1 * iv;
  axs[row][c0 + 2] = a2 * iv; axs[row][c0 + 3] = a3 * iv;
  __syncthreads();

  // hi = lrelu([xi, adjxi] @ w_eff)
  const float* wk = weff + (size_t)k * 2048;
  float h[4] = {0.f, 0.f, 0.f, 0.f};
  for (int u = 0; u < 32; ++u) {
    float xu = bf2f(xis[pglob * 36 + u]);
    float au = axs[row][u];
    const float* w0 = wk + u * 32 + c0;
    const float* w1 = wk + (32 + u) * 32 + c0;
#pragma unroll
    for (int j = 0; j < 4; ++j) h[j] += xu * w0[j] + au * w1[j];
  }
  float* hrow = hi + (size_t)k * 8192 + (size_t)pglob * 32 + c0;
  float vs[4], vq[4];
#pragma unroll
  for (int j = 0; j < 4; ++j) {
    float v = fmaxf(h[j], 0.2f * h[j]);
    hrow[j] = v;
    vs[j] = v; vq[j] = v * v;
  }
#pragma unroll
  for (int j = 0; j < 4; ++j) {
#pragma unroll
    for (int mm = 8; mm < 64; mm <<= 1) {
      vs[j] += __shfl_xor(vs[j], mm);
      vq[j] += __shfl_xor(vq[j], mm);
    }
  }
  if ((tid & 56) == 0) {       // one row-rep per wave
#pragma unroll
    for (int j = 0; j < 4; ++j) {
      atomicAdd(&s3[(c0 + j) * 2 + 0], vs[j]);
      atomicAdd(&s3[(c0 + j) * 2 + 1], vq[j]);
    }
  }
  __syncthreads();
  if (tid < 64) atomicAdd(&stats3[k * 64 + tid], s3[tid]);
}

// ------------------------------ BN3 + scatter -------------------------------
__global__ __launch_bounds__(256) void k_bn3(
    const float* __restrict__ hi, const float* __restrict__ stats3,
    const float* __restrict__ g3, const float* __restrict__ b3,
    const int* __restrict__ order, float* __restrict__ xnew) {
  int idx = blockIdx.x * 256 + threadIdx.x;   // 131072
  int k = idx >> 13, r = (idx >> 5) & 255, c = idx & 31;
  float sum = stats3[k * 64 + c * 2], sq = stats3[k * 64 + c * 2 + 1];
  const float invN = 1.f / 256.f;
  float mean = sum * invN;
  float var = sq * invN - mean * mean;
  float s = g3[k * 32 + c] * rsqrtf(fmaxf(var, 0.f) + 1e-5f);
  float t = b3[k * 32 + c] - mean * s;
  xnew[(size_t)order[k * 256 + r] * 32 + c] = hi[idx] * s + t;
}

// ------------------------------- final add ----------------------------------
__global__ __launch_bounds__(256) void k_final(const float* __restrict__ xc,
                                               const float* __restrict__ xnew,
                                               float* __restrict__ out) {
  int idx = blockIdx.x * 256 + threadIdx.x;   // 2097152 float4 groups
  int c4 = idx & 7, v = idx >> 3;
  int z = v & 63, y = (v >> 6) & 63, x = v >> 12;
  int sx = (x >> 2) + (x & 3) - 1;
  int sy = (y >> 2) + (y & 3) - 1;
  int sz = (z >> 2) + (z & 3) - 1;
  f32x4 add = {0.f, 0.f, 0.f, 0.f};
  if ((unsigned)sx < 16u && (unsigned)sy < 16u && (unsigned)sz < 16u)
    add = *(const f32x4*)&xnew[(size_t)(((sx << 4) + sy) * 16 + sz) * 32 + c4 * 4];
  const f32x4 a = *(const f32x4*)&xc[(size_t)idx * 4];
  *(f32x4*)&out[(size_t)idx * 4] = a + add;
}

// ----------------------------------------------------------------------------
extern "C" void kernel_launch(void* const* d_in, const int* in_sizes, int n_in,
                              void* d_out, int out_size, void* d_ws, size_t ws_size,
                              hipStream_t stream) {
  const float* xc   = (const float*)d_in[0];
  const int*   ci   = (const int*)  d_in[1];
  const float* c1w  = (const float*)d_in[2];
  const float* bn1g = (const float*)d_in[4];
  const float* bn1b = (const float*)d_in[5];
  const float* c2w  = (const float*)d_in[6];
  const float* bn2g = (const float*)d_in[8];
  const float* bn2b = (const float*)d_in[9];
  const float* c3w  = (const float*)d_in[10];
  const float* gcnw = (const float*)d_in[12];
  const float* bn3g = (const float*)d_in[13];
  const float* bn3b = (const float*)d_in[14];
  const float* mw1  = (const float*)d_in[15];
  const float* mb1  = (const float*)d_in[16];
  const float* mw2  = (const float*)d_in[17];
  const float* mb2  = (const float*)d_in[18];
  const float* mw3  = (const float*)d_in[19];
  const float* mb3  = (const float*)d_in[20];

  float* wsf = (float*)d_ws;
  float*  x      = wsf + 0;          // 131072
  float*  xi     = wsf + 131072;     // 131072
  float*  xnew   = wsf + 262144;     // 131072
  float*  hi     = wsf + 393216;     // 131072
  float*  weff   = wsf + 524288;     // 32768
  float*  stats1 = wsf + 557056;     // 2048
  float*  stats2 = wsf + 559104;     // 3072
  float*  stats3 = wsf + 562176;     // 1024
  float2* coef1  = (float2*)(wsf + 563200);  // 2048 floats
  float2* coef2  = (float2*)(wsf + 565248);  // 3072 floats
  float*  logits = wsf + 568320;     // 1048576
  unsigned char* wsb = (unsigned char*)d_ws;
  int* order = (int*)(wsb + 6467584);
  unsigned short* w1b = (unsigned short*)(wsb + 6467584 + 16384);
  unsigned short* w2b = (unsigned short*)(wsb + 6467584 + 16384 + 65536);

  hipMemsetAsync(stats1, 0, 6144 * sizeof(float), stream);  // stats1|2|3
  k_pool <<<512, 256, 0, stream>>>(xc, x);
  k_wcvt <<<384, 256, 0, stream>>>(c1w, c2w, w1b, w2b);
  k_order<<<16, 256, 0, stream>>>(ci, x, order, xi);
  k_mlp  <<<16, 256, 0, stream>>>(xi, mw1, mb1, mw2, mb2, mw3, mb3, gcnw, weff);
  dim3 gconv(128, 16);
  k_conv<0><<<gconv, 256, 0, stream>>>(xi, w1b, w2b, coef1, coef2, c3w, stats1, stats2, logits);
  k_bnco <<<4, 256, 0, stream>>>(stats1, bn1g, bn1b, coef1, 64);
  k_conv<1><<<gconv, 256, 0, stream>>>(xi, w1b, w2b, coef1, coef2, c3w, stats1, stats2, logits);
  k_bnco <<<6, 256, 0, stream>>>(stats2, bn2g, bn2b, coef2, 96);
  k_conv<2><<<gconv, 256, 0, stream>>>(xi, w1b, w2b, coef1, coef2, c3w, stats1, stats2, logits);
  k_graph<<<dim3(8, 16), 256, 0, stream>>>(xi, logits, weff, hi, stats3);
  k_bn3  <<<512, 256, 0, stream>>>(hi, stats3, bn3g, bn3b, order, xnew);
  k_final<<<8192, 256, 0, stream>>>(xc, xnew, (float*)d_out);
}

// Round 2
// 177.118 us; speedup vs baseline: 1.3233x; 1.3233x over previous
//
#include <hip/hip_runtime.h>
#include <hip/hip_bf16.h>

// ---------------------------------------------------------------------------
// ClusterGNN fused pipeline for MI355X (gfx950).  Round 1.
//   - k_mlp split into 3 kernels (was 62us latency-bound on 16 blocks).
//   - k_conv re-tiled to exploit logits symmetry: 32x32 pair tiles, upper
//     triangle only (36 tiles/cluster), stats weighted x2 off-diagonal,
//     logits mirror-written.  q-rows in registers, p-rows in 4KB LDS.
// ---------------------------------------------------------------------------

typedef short bfrag8 __attribute__((ext_vector_type(8)));   // 8 bf16 (4 VGPR)
typedef float f32x4  __attribute__((ext_vector_type(4)));

#define DI __device__ __forceinline__

DI unsigned short f2bf(float f) {
  return __builtin_bit_cast(unsigned short, __float2bfloat16(f));
}
DI float bf2f(unsigned short u) {
  return __builtin_bit_cast(float, ((unsigned)u) << 16);
}

// ------------------------------- pool --------------------------------------
__global__ __launch_bounds__(256) void k_pool(const float* __restrict__ xc,
                                              float* __restrict__ x) {
  int idx = blockIdx.x * 256 + threadIdx.x;      // 131072 = 4096*32
  int c = idx & 31, g = idx >> 5;
  int gz = g & 15, gy = (g >> 4) & 15, gx = g >> 8;
  float s = 0.f;
  for (int ix = 0; ix < 4; ++ix)
    for (int iy = 0; iy < 4; ++iy)
      for (int iz = 0; iz < 4; ++iz) {
        int X = gx * 4 + ix, Y = gy * 4 + iy, Z = gz * 4 + iz;
        s += xc[(size_t)(((X << 6) | Y) << 6 | Z) * 32 + c];
      }
  x[idx] = s * (1.f / 64.f);
}

// --------------------------- order + gather --------------------------------
__global__ __launch_bounds__(256) void k_order(const int* __restrict__ ci,
                                               const float* __restrict__ x,
                                               int* __restrict__ order,
                                               float* __restrict__ xi) {
  const int k = blockIdx.x, t = threadIdx.x;
  __shared__ int scnt[256];
  __shared__ int ordl[256];
  int match[16];
  int cnt = 0;
#pragma unroll
  for (int j = 0; j < 16; ++j) { match[j] = (ci[t * 16 + j] == k); cnt += match[j]; }
  scnt[t] = cnt;
  __syncthreads();
  for (int off = 1; off < 256; off <<= 1) {        // inclusive Hillis-Steele
    int v = (t >= off) ? scnt[t - off] : 0;
    __syncthreads();
    scnt[t] += v;
    __syncthreads();
  }
  int pos = scnt[t] - cnt;                         // exclusive
#pragma unroll
  for (int j = 0; j < 16; ++j)
    if (match[j]) ordl[pos++] = t * 16 + j;
  __syncthreads();
  int src = ordl[t];
  order[k * 256 + t] = src;
  const f32x4* xr = (const f32x4*)(x + (size_t)src * 32);
  f32x4* xo = (f32x4*)(xi + ((size_t)k * 256 + t) * 32);
#pragma unroll
  for (int c = 0; c < 8; ++c) xo[c] = xr[c];
}

// ---------------------------- weight cvt -----------------------------------
__global__ __launch_bounds__(256) void k_wcvt(const float* __restrict__ w1,
                                              const float* __restrict__ w2,
                                              unsigned short* __restrict__ w1b,
                                              unsigned short* __restrict__ w2b) {
  int i = blockIdx.x * 256 + threadIdx.x;
  if (i < 32768) w1b[i] = f2bf(w1[i]);
  if (i < 98304) w2b[i] = f2bf(w2[i]);
}

// ------------------------------- MLP (split) --------------------------------
__global__ __launch_bounds__(256) void k_mlp1(
    const float* __restrict__ xi,
    const float* __restrict__ mw1, const float* __restrict__ mb1,
    const float* __restrict__ mw2, const float* __restrict__ mb2,
    float* __restrict__ h2buf) {
  const int k = blockIdx.x, t = threadIdx.x;
  __shared__ float red[256];
  __shared__ float cent[32];
  __shared__ float h1[128];
  const float* xk = xi + (size_t)k * 8192;
  {
    int c = t & 31, rp = t >> 5;
    float ssum = 0.f;
    for (int r = rp; r < 256; r += 8) ssum += xk[r * 32 + c];
    red[t] = ssum;
  }
  __syncthreads();
  if (t < 32) {
    float tot = 0.f;
#pragma unroll
    for (int g = 0; g < 8; ++g) tot += red[g * 32 + t];
    cent[t] = tot * (1.f / 256.f);
  }
  __syncthreads();
  if (t < 128) {
    float s = mb1[t];
#pragma unroll
    for (int c = 0; c < 32; ++c) s += cent[c] * mw1[c * 128 + t];
    h1[t] = fmaxf(s, 0.f);
  }
  __syncthreads();
  float s = mb2[t];
  for (int j = 0; j < 128; ++j) s += h1[j] * mw2[j * 256 + t];
  h2buf[k * 256 + t] = fmaxf(s, 0.f);
}

__global__ __launch_bounds__(256) void k_mlp2(
    const float* __restrict__ h2buf,
    const float* __restrict__ mw3, const float* __restrict__ mb3,
    float* __restrict__ swb) {
  const int k = blockIdx.y, t = threadIdx.x;
  const int o = blockIdx.x * 256 + t;
  __shared__ float h2s[256];
  h2s[t] = h2buf[k * 256 + t];
  __syncthreads();
  float s = mb3[o];
  for (int j = 0; j < 256; ++j) s += h2s[j] * mw3[j * 1024 + o];
  swb[k * 1024 + o] = 1.f / (1.f + __expf(-s));
}

__global__ __launch_bounds__(256) void k_mlp3(
    const float* __restrict__ swb,
    const float* __restrict__ gcnw,
    float* __restrict__ weff) {
  const int k = blockIdx.y, t = threadIdx.x;
  const int e = blockIdx.x * 256 + t;           // 0..2047
  __shared__ float swl[1024];
#pragma unroll
  for (int j = 0; j < 4; ++j) swl[t + j * 256] = swb[k * 1024 + t + j * 256];
  __syncthreads();
  const int u = e >> 5, v = e & 31;
  const float* gk = gcnw + (size_t)k * 2048;
  float s = 0.f;
#pragma unroll
  for (int ss = 0; ss < 32; ++ss) s += gk[u * 32 + ss] * swl[ss * 32 + v];
  weff[(size_t)k * 2048 + e] = s;
}

// --------------------------- fused pair chain -------------------------------
// Symmetric tiling: per cluster, 36 tiles (a<=b) of 32p x 32q.  Block = 4
// waves; wave wv handles p in [Pb+8wv, Pb+8wv+8), all 32 q-rows.  q-rows in
// registers, p-rows in LDS.  Stats weighted (1 diag / 2 off-diag); logits
// mirror-written for off-diag tiles.
template <int MODE>
__global__ __launch_bounds__(256) void k_conv(
    const float* __restrict__ xi,
    const unsigned short* __restrict__ w1b,
    const unsigned short* __restrict__ w2b,
    const float2* __restrict__ coef1,
    const float2* __restrict__ coef2,
    const float* __restrict__ conv3w,
    float* __restrict__ stats1,
    float* __restrict__ stats2,
    float* __restrict__ logits) {
  const int k   = blockIdx.y;
  const int t36 = blockIdx.x;            // 0..35 upper-triangle tile
  int a = 0, rem = t36;
  while (rem >= 8 - a) { rem -= 8 - a; ++a; }
  const int b = a + rem;                 // a<=b
  const int Pb = a * 32, Qb = b * 32;
  const float w = (a == b) ? 1.f : 2.f;

  const int tid = threadIdx.x;
  const int lane = tid & 63;
  const int wv  = tid >> 6;              // wave 0..3
  const int l15 = lane & 15;
  const int lg  = lane >> 4;             // 0..3

  __shared__ __align__(16) float xp[32][32];                 // p rows
  constexpr int NF = (MODE == 0) ? 4 : 6;
  constexpr int A1SZ = (MODE >= 1) ? 4 * 32 * 72 : 8;
  __shared__ __align__(16) unsigned short a1s[A1SZ];
  __shared__ float sred[192];

  const float* xik = xi + (size_t)k * (256 * 32);

  {  // stage 32 p rows
    const int r = tid >> 3, c4 = (tid & 7) * 4;
    *(f32x4*)&xp[r][c4] = *(const f32x4*)(xik + (size_t)(Pb + r) * 32 + c4);
  }

  // q rows in registers: rows Qb+rt*16+l15, cols lg*8..+8
  float qv[2][8];
#pragma unroll
  for (int rt = 0; rt < 2; ++rt) {
    const float* qr = xik + (size_t)(Qb + rt * 16 + l15) * 32 + lg * 8;
    f32x4 v0 = *(const f32x4*)qr;
    f32x4 v1 = *(const f32x4*)(qr + 4);
#pragma unroll
    for (int j = 0; j < 4; ++j) { qv[rt][j] = v0[j]; qv[rt][4 + j] = v1[j]; }
  }

  // B fragments / coefficients (per-lane, L2 resident)
  bfrag8 B1[4];
  {
    const unsigned short* w1k = w1b + k * (64 * 32);
#pragma unroll
    for (int f = 0; f < 4; ++f)
      B1[f] = *(const bfrag8*)(w1k + (16 * f + l15) * 32 + lg * 8);
  }
  bfrag8 B2[6][2];
  float2 c1[4];
  float2 c2[6];
  float w3v[6];
  if constexpr (MODE >= 1) {
    const unsigned short* w2k = w2b + k * (96 * 64);
#pragma unroll
    for (int f = 0; f < 6; ++f) {
      B2[f][0] = *(const bfrag8*)(w2k + (16 * f + l15) * 64 + lg * 8);
      B2[f][1] = *(const bfrag8*)(w2k + (16 * f + l15) * 64 + 32 + lg * 8);
    }
#pragma unroll
    for (int f = 0; f < 4; ++f) c1[f] = coef1[k * 64 + 16 * f + l15];
  }
  if constexpr (MODE == 2) {
#pragma unroll
    for (int f = 0; f < 6; ++f) {
      c2[f]  = coef2[k * 96 + 16 * f + l15];
      w3v[f] = conv3w[k * 96 + 16 * f + l15];
    }
  }

  float ssum[6], ssq[6];
#pragma unroll
  for (int f = 0; f < 6; ++f) { ssum[f] = 0.f; ssq[f] = 0.f; }

  __syncthreads();

  for (int pl = 0; pl < 8; ++pl) {
    const int plocal = wv * 8 + pl;
    const int pglob  = Pb + plocal;
    float pv[8];
    {
      const float* xpp = &xp[plocal][lg * 8];
#pragma unroll
      for (int j = 0; j < 8; ++j) pv[j] = xpp[j];
    }
#pragma unroll
    for (int rt = 0; rt < 2; ++rt) {
      bfrag8 af;
#pragma unroll
      for (int j = 0; j < 8; ++j) af[j] = (short)f2bf(fabsf(qv[rt][j] - pv[j]));
      const f32x4 z = {0.f, 0.f, 0.f, 0.f};
      f32x4 acc1[4];
#pragma unroll
      for (int f = 0; f < 4; ++f)
        acc1[f] = __builtin_amdgcn_mfma_f32_16x16x32_bf16(af, B1[f], z, 0, 0, 0);
      if constexpr (MODE == 0) {
#pragma unroll
        for (int f = 0; f < 4; ++f)
#pragma unroll
          for (int r = 0; r < 4; ++r) { float h = acc1[f][r]; ssum[f] += h; ssq[f] += h * h; }
      } else {
        unsigned short* aw = &a1s[wv * 2304 + (rt * 16 + lg * 4) * 72 + l15];
#pragma unroll
        for (int f = 0; f < 4; ++f)
#pragma unroll
          for (int r = 0; r < 4; ++r) {
            float h = acc1[f][r] * c1[f].x + c1[f].y;
            h = fmaxf(h, 0.2f * h);
            aw[r * 72 + 16 * f] = f2bf(h);
          }
      }
    }
    if constexpr (MODE >= 1) {
#pragma unroll
      for (int rt = 0; rt < 2; ++rt) {
        bfrag8 A0 = *(const bfrag8*)&a1s[wv * 2304 + (rt * 16 + l15) * 72 + lg * 8];
        bfrag8 A1 = *(const bfrag8*)&a1s[wv * 2304 + (rt * 16 + l15) * 72 + 32 + lg * 8];
        f32x4 acc2[6];
#pragma unroll
        for (int f = 0; f < 6; ++f) {
          f32x4 acc = {0.f, 0.f, 0.f, 0.f};
          acc = __builtin_amdgcn_mfma_f32_16x16x32_bf16(A0, B2[f][0], acc, 0, 0, 0);
          acc = __builtin_amdgcn_mfma_f32_16x16x32_bf16(A1, B2[f][1], acc, 0, 0, 0);
          acc2[f] = acc;
        }
        if constexpr (MODE == 1) {
#pragma unroll
          for (int f = 0; f < 6; ++f)
#pragma unroll
            for (int r = 0; r < 4; ++r) { float h = acc2[f][r]; ssum[f] += h; ssq[f] += h * h; }
        } else {
          f32x4 lp = {0.f, 0.f, 0.f, 0.f};
#pragma unroll
          for (int f = 0; f < 6; ++f)
#pragma unroll
            for (int r = 0; r < 4; ++r) {
              float h = acc2[f][r] * c2[f].x + c2[f].y;
              h = fmaxf(h, 0.2f * h);
              lp[r] += h * w3v[f];
            }
#pragma unroll
          for (int m = 1; m < 16; m <<= 1) {
            lp[0] += __shfl_xor(lp[0], m);
            lp[1] += __shfl_xor(lp[1], m);
            lp[2] += __shfl_xor(lp[2], m);
            lp[3] += __shfl_xor(lp[3], m);
          }
          if (l15 == 0) {
            const int q0 = Qb + rt * 16 + lg * 4;
            *(f32x4*)&logits[(size_t)k * 65536 + (size_t)pglob * 256 + q0] = lp;
            if (a != b) {
#pragma unroll
              for (int r = 0; r < 4; ++r)
                logits[(size_t)k * 65536 + (size_t)(q0 + r) * 256 + pglob] = lp[r];
            }
          }
        }
      }
    }
  }

  if constexpr (MODE <= 1) {
#pragma unroll
    for (int f = 0; f < NF; ++f) {
      ssum[f] += __shfl_xor(ssum[f], 16); ssum[f] += __shfl_xor(ssum[f], 32);
      ssq[f]  += __shfl_xor(ssq[f], 16);  ssq[f]  += __shfl_xor(ssq[f], 32);
    }
    __syncthreads();
    if (tid < 2 * 16 * NF) sred[tid] = 0.f;
    __syncthreads();
    if (lg == 0) {
#pragma unroll
      for (int f = 0; f < NF; ++f) {
        atomicAdd(&sred[(16 * f + l15) * 2 + 0], ssum[f] * w);
        atomicAdd(&sred[(16 * f + l15) * 2 + 1], ssq[f] * w);
      }
    }
    __syncthreads();
    float* gs = (MODE == 0) ? stats1 : stats2;
    if (tid < 2 * 16 * NF) atomicAdd(&gs[k * (2 * 16 * NF) + tid], sred[tid]);
  }
}

// ------------------------- BN coefficient kernel ----------------------------
__global__ void k_bnco(const float* __restrict__ stats,
                       const float* __restrict__ g,
                       const float* __restrict__ b,
                       float2* __restrict__ coef, int nch) {
  int i = blockIdx.x * 256 + threadIdx.x;
  if (i >= 16 * nch) return;
  float sum = stats[i * 2], sq = stats[i * 2 + 1];
  const float invN = 1.f / 65536.f;
  float mean = sum * invN;
  float var = sq * invN - mean * mean;
  float s = g[i] * rsqrtf(fmaxf(var, 0.f) + 1e-5f);
  coef[i] = make_float2(s, b[i] - mean * s);
}

// --------------------- softmax + adj@xi + GCN + BN3 stats -------------------
__global__ __launch_bounds__(256) void k_graph(
    const float* __restrict__ xi,
    const float* __restrict__ logits,
    const float* __restrict__ weff,
    float* __restrict__ hi,
    float* __restrict__ stats3) {
  const int k  = blockIdx.y;
  const int pc = blockIdx.x;   // 0..7, 32 rows each
  const int tid = threadIdx.x;
  __shared__ unsigned short xis[256 * 36];   // bf16 xi, pad 36
  __shared__ float es[32][258];
  __shared__ float axs[32][33];
  __shared__ float inv_s[32];
  __shared__ float s3[64];

  const float* xik = xi + (size_t)k * 8192;
  for (int i = tid; i < 8192; i += 256) {
    int r = i >> 5, c = i & 31;
    xis[r * 36 + c] = f2bf(xik[i]);
  }
  if (tid < 64) s3[tid] = 0.f;
  __syncthreads();

  const int row = tid >> 3;    // 0..31
  const int s   = tid & 7;
  const int pglob = pc * 32 + row;
  const float* lrow = logits + (size_t)k * 65536 + (size_t)pglob * 256;

  float m = -1e30f;
  for (int q = s; q < 256; q += 8) {
    float v = lrow[q];
    m = (q == pglob) ? m : fmaxf(m, v);
  }
  m = fmaxf(m, __shfl_xor(m, 1));
  m = fmaxf(m, __shfl_xor(m, 2));
  m = fmaxf(m, __shfl_xor(m, 4));
  float sum = 0.f;
  for (int q = s; q < 256; q += 8) {
    float e = (q == pglob) ? 0.f : __expf(lrow[q] - m);
    es[row][q] = e;
    sum += e;
  }
  sum += __shfl_xor(sum, 1);
  sum += __shfl_xor(sum, 2);
  sum += __shfl_xor(sum, 4);
  if (s == 0) inv_s[row] = 1.f / sum;
  __syncthreads();

  const int c0 = s * 4;
  float a0 = 0.f, a1 = 0.f, a2 = 0.f, a3 = 0.f;
  for (int q = 0; q < 256; ++q) {
    float e = es[row][q];
    const unsigned short* xr = &xis[q * 36 + c0];
    a0 += e * bf2f(xr[0]);
    a1 += e * bf2f(xr[1]);
    a2 += e * bf2f(xr[2]);
    a3 += e * bf2f(xr[3]);
  }
  float iv = inv_s[row];
  axs[row][c0 + 0] = a0 * iv; axs[row][c0 + 1] = a1 * iv;
  axs[row][c0 + 2] = a2 * iv; axs[row][c0 + 3] = a3 * iv;
  __syncthreads();

  const float* wk = weff + (size_t)k * 2048;
  float h[4] = {0.f, 0.f, 0.f, 0.f};
  for (int u = 0; u < 32; ++u) {
    float xu = bf2f(xis[pglob * 36 + u]);
    float au = axs[row][u];
    const float* w0 = wk + u * 32 + c0;
    const float* w1 = wk + (32 + u) * 32 + c0;
#pragma unroll
    for (int j = 0; j < 4; ++j) h[j] += xu * w0[j] + au * w1[j];
  }
  float* hrow = hi + (size_t)k * 8192 + (size_t)pglob * 32 + c0;
  float vs[4], vq[4];
#pragma unroll
  for (int j = 0; j < 4; ++j) {
    float v = fmaxf(h[j], 0.2f * h[j]);
    hrow[j] = v;
    vs[j] = v; vq[j] = v * v;
  }
#pragma unroll
  for (int j = 0; j < 4; ++j) {
#pragma unroll
    for (int mm = 8; mm < 64; mm <<= 1) {
      vs[j] += __shfl_xor(vs[j], mm);
      vq[j] += __shfl_xor(vq[j], mm);
    }
  }
  if ((tid & 56) == 0) {
#pragma unroll
    for (int j = 0; j < 4; ++j) {
      atomicAdd(&s3[(c0 + j) * 2 + 0], vs[j]);
      atomicAdd(&s3[(c0 + j) * 2 + 1], vq[j]);
    }
  }
  __syncthreads();
  if (tid < 64) atomicAdd(&stats3[k * 64 + tid], s3[tid]);
}

// ------------------------------ BN3 + scatter -------------------------------
__global__ __launch_bounds__(256) void k_bn3(
    const float* __restrict__ hi, const float* __restrict__ stats3,
    const float* __restrict__ g3, const float* __restrict__ b3,
    const int* __restrict__ order, float* __restrict__ xnew) {
  int idx = blockIdx.x * 256 + threadIdx.x;   // 131072
  int k = idx >> 13, r = (idx >> 5) & 255, c = idx & 31;
  float sum = stats3[k * 64 + c * 2], sq = stats3[k * 64 + c * 2 + 1];
  const float invN = 1.f / 256.f;
  float mean = sum * invN;
  float var = sq * invN - mean * mean;
  float s = g3[k * 32 + c] * rsqrtf(fmaxf(var, 0.f) + 1e-5f);
  float t = b3[k * 32 + c] - mean * s;
  xnew[(size_t)order[k * 256 + r] * 32 + c] = hi[idx] * s + t;
}

// ------------------------------- final add ----------------------------------
__global__ __launch_bounds__(256) void k_final(const float* __restrict__ xc,
                                               const float* __restrict__ xnew,
                                               float* __restrict__ out) {
  int idx = blockIdx.x * 256 + threadIdx.x;   // 2097152 float4 groups
  int c4 = idx & 7, v = idx >> 3;
  int z = v & 63, y = (v >> 6) & 63, x = v >> 12;
  int sx = (x >> 2) + (x & 3) - 1;
  int sy = (y >> 2) + (y & 3) - 1;
  int sz = (z >> 2) + (z & 3) - 1;
  f32x4 add = {0.f, 0.f, 0.f, 0.f};
  if ((unsigned)sx < 16u && (unsigned)sy < 16u && (unsigned)sz < 16u)
    add = *(const f32x4*)&xnew[(size_t)(((sx << 4) + sy) * 16 + sz) * 32 + c4 * 4];
  const f32x4 a = *(const f32x4*)&xc[(size_t)idx * 4];
  *(f32x4*)&out[(size_t)idx * 4] = a + add;
}

// ----------------------------------------------------------------------------
extern "C" void kernel_launch(void* const* d_in, const int* in_sizes, int n_in,
                              void* d_out, int out_size, void* d_ws, size_t ws_size,
                              hipStream_t stream) {
  const float* xc   = (const float*)d_in[0];
  const int*   ci   = (const int*)  d_in[1];
  const float* c1w  = (const float*)d_in[2];
  const float* bn1g = (const float*)d_in[4];
  const float* bn1b = (const float*)d_in[5];
  const float* c2w  = (const float*)d_in[6];
  const float* bn2g = (const float*)d_in[8];
  const float* bn2b = (const float*)d_in[9];
  const float* c3w  = (const float*)d_in[10];
  const float* gcnw = (const float*)d_in[12];
  const float* bn3g = (const float*)d_in[13];
  const float* bn3b = (const float*)d_in[14];
  const float* mw1  = (const float*)d_in[15];
  const float* mb1  = (const float*)d_in[16];
  const float* mw2  = (const float*)d_in[17];
  const float* mb2  = (const float*)d_in[18];
  const float* mw3  = (const float*)d_in[19];
  const float* mb3  = (const float*)d_in[20];

  float* wsf = (float*)d_ws;
  float*  x      = wsf + 0;          // 131072 (dead after k_order; reused below)
  float*  xi     = wsf + 131072;     // 131072
  float*  xnew   = wsf + 262144;     // 131072
  float*  hi     = wsf + 393216;     // 131072
  float*  weff   = wsf + 524288;     // 32768
  float*  stats1 = wsf + 557056;     // 2048
  float*  stats2 = wsf + 559104;     // 3072
  float*  stats3 = wsf + 562176;     // 1024
  float2* coef1  = (float2*)(wsf + 563200);  // 2048 floats
  float2* coef2  = (float2*)(wsf + 565248);  // 3072 floats
  float*  logits = wsf + 568320;     // 1048576
  unsigned char* wsb = (unsigned char*)d_ws;
  int* order = (int*)(wsb + 6467584);
  unsigned short* w1b = (unsigned short*)(wsb + 6467584 + 16384);
  unsigned short* w2b = (unsigned short*)(wsb + 6467584 + 16384 + 65536);
  // MLP scratch aliases the dead x region (x consumed by k_order before k_mlp1)
  float* h2mlp = x;                  // 4096 floats
  float* swb   = x + 4096;           // 16384 floats

  hipMemsetAsync(stats1, 0, 6144 * sizeof(float), stream);  // stats1|2|3
  k_pool <<<512, 256, 0, stream>>>(xc, x);
  k_wcvt <<<384, 256, 0, stream>>>(c1w, c2w, w1b, w2b);
  k_order<<<16, 256, 0, stream>>>(ci, x, order, xi);
  k_mlp1 <<<16, 256, 0, stream>>>(xi, mw1, mb1, mw2, mb2, h2mlp);
  k_mlp2 <<<dim3(4, 16), 256, 0, stream>>>(h2mlp, mw3, mb3, swb);
  k_mlp3 <<<dim3(8, 16), 256, 0, stream>>>(swb, gcnw, weff);
  dim3 gconv(36, 16);
  k_conv<0><<<gconv, 256, 0, stream>>>(xi, w1b, w2b, coef1, coef2, c3w, stats1, stats2, logits);
  k_bnco <<<4, 256, 0, stream>>>(stats1, bn1g, bn1b, coef1, 64);
  k_conv<1><<<gconv, 256, 0, stream>>>(xi, w1b, w2b, coef1, coef2, c3w, stats1, stats2, logits);
  k_bnco <<<6, 256, 0, stream>>>(stats2, bn2g, bn2b, coef2, 96);
  k_conv<2><<<gconv, 256, 0, stream>>>(xi, w1b, w2b, coef1, coef2, c3w, stats1, stats2, logits);
  k_graph<<<dim3(8, 16), 256, 0, stream>>>(xi, logits, weff, hi, stats3);
  k_bn3  <<<512, 256, 0, stream>>>(hi, stats3, bn3g, bn3b, order, xnew);
  k_final<<<8192, 256, 0, stream>>>(xc, xnew, (float*)d_out);
}

// Round 3
// 175.949 us; speedup vs baseline: 1.3321x; 1.0066x over previous
//
#include <hip/hip_runtime.h>
#include <hip/hip_bf16.h>

// ---------------------------------------------------------------------------
// ClusterGNN fused pipeline for MI355X (gfx950).  Round 1.
//   - k_mlp split into 3 kernels (was 62us latency-bound on 16 blocks).
//   - k_conv re-tiled to exploit logits symmetry: 32x32 pair tiles, upper
//     triangle only (36 tiles/cluster), stats weighted x2 off-diagonal,
//     logits mirror-written.  q-rows in registers, p-rows in 4KB LDS.
// ---------------------------------------------------------------------------

typedef short bfrag8 __attribute__((ext_vector_type(8)));   // 8 bf16 (4 VGPR)
typedef float f32x4  __attribute__((ext_vector_type(4)));

#define DI __device__ __forceinline__

DI unsigned short f2bf(float f) {
  return __builtin_bit_cast(unsigned short, __float2bfloat16(f));
}
DI float bf2f(unsigned short u) {
  return __builtin_bit_cast(float, ((unsigned)u) << 16);
}

// ------------------------------- pool --------------------------------------
__global__ __launch_bounds__(256) void k_pool(const float* __restrict__ xc,
                                              float* __restrict__ x) {
  int idx = blockIdx.x * 256 + threadIdx.x;      // 131072 = 4096*32
  int c = idx & 31, g = idx >> 5;
  int gz = g & 15, gy = (g >> 4) & 15, gx = g >> 8;
  float s = 0.f;
  for (int ix = 0; ix < 4; ++ix)
    for (int iy = 0; iy < 4; ++iy)
      for (int iz = 0; iz < 4; ++iz) {
        int X = gx * 4 + ix, Y = gy * 4 + iy, Z = gz * 4 + iz;
        s += xc[(size_t)(((X << 6) | Y) << 6 | Z) * 32 + c];
      }
  x[idx] = s * (1.f / 64.f);
}

// --------------------------- order + gather --------------------------------
__global__ __launch_bounds__(256) void k_order(const int* __restrict__ ci,
                                               const float* __restrict__ x,
                                               int* __restrict__ order,
                                               float* __restrict__ xi) {
  const int k = blockIdx.x, t = threadIdx.x;
  __shared__ int scnt[256];
  __shared__ int ordl[256];
  int match[16];
  int cnt = 0;
#pragma unroll
  for (int j = 0; j < 16; ++j) { match[j] = (ci[t * 16 + j] == k); cnt += match[j]; }
  scnt[t] = cnt;
  __syncthreads();
  for (int off = 1; off < 256; off <<= 1) {        // inclusive Hillis-Steele
    int v = (t >= off) ? scnt[t - off] : 0;
    __syncthreads();
    scnt[t] += v;
    __syncthreads();
  }
  int pos = scnt[t] - cnt;                         // exclusive
#pragma unroll
  for (int j = 0; j < 16; ++j)
    if (match[j]) ordl[pos++] = t * 16 + j;
  __syncthreads();
  int src = ordl[t];
  order[k * 256 + t] = src;
  const f32x4* xr = (const f32x4*)(x + (size_t)src * 32);
  f32x4* xo = (f32x4*)(xi + ((size_t)k * 256 + t) * 32);
#pragma unroll
  for (int c = 0; c < 8; ++c) xo[c] = xr[c];
}

// ---------------------------- weight cvt -----------------------------------
__global__ __launch_bounds__(256) void k_wcvt(const float* __restrict__ w1,
                                              const float* __restrict__ w2,
                                              unsigned short* __restrict__ w1b,
                                              unsigned short* __restrict__ w2b) {
  int i = blockIdx.x * 256 + threadIdx.x;
  if (i < 32768) w1b[i] = f2bf(w1[i]);
  if (i < 98304) w2b[i] = f2bf(w2[i]);
}

// ------------------------------- MLP (split) --------------------------------
__global__ __launch_bounds__(256) void k_mlp1(
    const float* __restrict__ xi,
    const float* __restrict__ mw1, const float* __restrict__ mb1,
    const float* __restrict__ mw2, const float* __restrict__ mb2,
    float* __restrict__ h2buf) {
  const int k = blockIdx.x, t = threadIdx.x;
  __shared__ float red[256];
  __shared__ float cent[32];
  __shared__ float h1[128];
  const float* xk = xi + (size_t)k * 8192;
  {
    int c = t & 31, rp = t >> 5;
    float ssum = 0.f;
    for (int r = rp; r < 256; r += 8) ssum += xk[r * 32 + c];
    red[t] = ssum;
  }
  __syncthreads();
  if (t < 32) {
    float tot = 0.f;
#pragma unroll
    for (int g = 0; g < 8; ++g) tot += red[g * 32 + t];
    cent[t] = tot * (1.f / 256.f);
  }
  __syncthreads();
  if (t < 128) {
    float s = mb1[t];
#pragma unroll
    for (int c = 0; c < 32; ++c) s += cent[c] * mw1[c * 128 + t];
    h1[t] = fmaxf(s, 0.f);
  }
  __syncthreads();
  float s = mb2[t];
  for (int j = 0; j < 128; ++j) s += h1[j] * mw2[j * 256 + t];
  h2buf[k * 256 + t] = fmaxf(s, 0.f);
}

__global__ __launch_bounds__(256) void k_mlp2(
    const float* __restrict__ h2buf,
    const float* __restrict__ mw3, const float* __restrict__ mb3,
    float* __restrict__ swb) {
  const int k = blockIdx.y, t = threadIdx.x;
  const int o = blockIdx.x * 256 + t;
  __shared__ float h2s[256];
  h2s[t] = h2buf[k * 256 + t];
  __syncthreads();
  float s = mb3[o];
  for (int j = 0; j < 256; ++j) s += h2s[j] * mw3[j * 1024 + o];
  swb[k * 1024 + o] = 1.f / (1.f + __expf(-s));
}

__global__ __launch_bounds__(256) void k_mlp3(
    const float* __restrict__ swb,
    const float* __restrict__ gcnw,
    float* __restrict__ weff) {
  const int k = blockIdx.y, t = threadIdx.x;
  const int e = blockIdx.x * 256 + t;           // 0..2047
  __shared__ float swl[1024];
#pragma unroll
  for (int j = 0; j < 4; ++j) swl[t + j * 256] = swb[k * 1024 + t + j * 256];
  __syncthreads();
  const int u = e >> 5, v = e & 31;
  const float* gk = gcnw + (size_t)k * 2048;
  float s = 0.f;
#pragma unroll
  for (int ss = 0; ss < 32; ++ss) s += gk[u * 32 + ss] * swl[ss * 32 + v];
  weff[(size_t)k * 2048 + e] = s;
}

// --------------------------- fused pair chain -------------------------------
// Symmetric tiling: per cluster, 36 tiles (a<=b) of 32p x 32q.  Block = 4
// waves; wave wv handles p in [Pb+8wv, Pb+8wv+8), all 32 q-rows.  q-rows in
// registers, p-rows in LDS.  Stats weighted (1 diag / 2 off-diag); logits
// mirror-written for off-diag tiles.
template <int MODE>
__global__ __launch_bounds__(256) void k_conv(
    const float* __restrict__ xi,
    const unsigned short* __restrict__ w1b,
    const unsigned short* __restrict__ w2b,
    const float2* __restrict__ coef1,
    const float2* __restrict__ coef2,
    const float* __restrict__ conv3w,
    float* __restrict__ stats1,
    float* __restrict__ stats2,
    float* __restrict__ logits) {
  const int k   = blockIdx.y;
  const int t36 = blockIdx.x;            // 0..35 upper-triangle tile
  int a = 0, rem = t36;
  while (rem >= 8 - a) { rem -= 8 - a; ++a; }
  const int b = a + rem;                 // a<=b
  const int Pb = a * 32, Qb = b * 32;
  const float w = (a == b) ? 1.f : 2.f;

  const int tid = threadIdx.x;
  const int lane = tid & 63;
  const int wv  = tid >> 6;              // wave 0..3
  const int l15 = lane & 15;
  const int lg  = lane >> 4;             // 0..3

  __shared__ __align__(16) float xp[32][32];                 // p rows
  constexpr int NF = (MODE == 0) ? 4 : 6;
  constexpr int A1SZ = (MODE >= 1) ? 4 * 32 * 72 : 8;
  __shared__ __align__(16) unsigned short a1s[A1SZ];
  __shared__ float sred[192];

  const float* xik = xi + (size_t)k * (256 * 32);

  {  // stage 32 p rows
    const int r = tid >> 3, c4 = (tid & 7) * 4;
    *(f32x4*)&xp[r][c4] = *(const f32x4*)(xik + (size_t)(Pb + r) * 32 + c4);
  }

  // q rows in registers: rows Qb+rt*16+l15, cols lg*8..+8
  float qv[2][8];
#pragma unroll
  for (int rt = 0; rt < 2; ++rt) {
    const float* qr = xik + (size_t)(Qb + rt * 16 + l15) * 32 + lg * 8;
    f32x4 v0 = *(const f32x4*)qr;
    f32x4 v1 = *(const f32x4*)(qr + 4);
#pragma unroll
    for (int j = 0; j < 4; ++j) { qv[rt][j] = v0[j]; qv[rt][4 + j] = v1[j]; }
  }

  // B fragments / coefficients (per-lane, L2 resident)
  bfrag8 B1[4];
  {
    const unsigned short* w1k = w1b + k * (64 * 32);
#pragma unroll
    for (int f = 0; f < 4; ++f)
      B1[f] = *(const bfrag8*)(w1k + (16 * f + l15) * 32 + lg * 8);
  }
  bfrag8 B2[6][2];
  float2 c1[4];
  float2 c2[6];
  float w3v[6];
  if constexpr (MODE >= 1) {
    const unsigned short* w2k = w2b + k * (96 * 64);
#pragma unroll
    for (int f = 0; f < 6; ++f) {
      B2[f][0] = *(const bfrag8*)(w2k + (16 * f + l15) * 64 + lg * 8);
      B2[f][1] = *(const bfrag8*)(w2k + (16 * f + l15) * 64 + 32 + lg * 8);
    }
#pragma unroll
    for (int f = 0; f < 4; ++f) c1[f] = coef1[k * 64 + 16 * f + l15];
  }
  if constexpr (MODE == 2) {
#pragma unroll
    for (int f = 0; f < 6; ++f) {
      c2[f]  = coef2[k * 96 + 16 * f + l15];
      w3v[f] = conv3w[k * 96 + 16 * f + l15];
    }
  }

  float ssum[6], ssq[6];
#pragma unroll
  for (int f = 0; f < 6; ++f) { ssum[f] = 0.f; ssq[f] = 0.f; }

  __syncthreads();

  for (int pl = 0; pl < 8; ++pl) {
    const int plocal = wv * 8 + pl;
    const int pglob  = Pb + plocal;
    float pv[8];
    {
      const float* xpp = &xp[plocal][lg * 8];
#pragma unroll
      for (int j = 0; j < 8; ++j) pv[j] = xpp[j];
    }
#pragma unroll
    for (int rt = 0; rt < 2; ++rt) {
      bfrag8 af;
#pragma unroll
      for (int j = 0; j < 8; ++j) af[j] = (short)f2bf(fabsf(qv[rt][j] - pv[j]));
      const f32x4 z = {0.f, 0.f, 0.f, 0.f};
      f32x4 acc1[4];
#pragma unroll
      for (int f = 0; f < 4; ++f)
        acc1[f] = __builtin_amdgcn_mfma_f32_16x16x32_bf16(af, B1[f], z, 0, 0, 0);
      if constexpr (MODE == 0) {
#pragma unroll
        for (int f = 0; f < 4; ++f)
#pragma unroll
          for (int r = 0; r < 4; ++r) { float h = acc1[f][r]; ssum[f] += h; ssq[f] += h * h; }
      } else {
        unsigned short* aw = &a1s[wv * 2304 + (rt * 16 + lg * 4) * 72 + l15];
#pragma unroll
        for (int f = 0; f < 4; ++f)
#pragma unroll
          for (int r = 0; r < 4; ++r) {
            float h = acc1[f][r] * c1[f].x + c1[f].y;
            h = fmaxf(h, 0.2f * h);
            aw[r * 72 + 16 * f] = f2bf(h);
          }
      }
    }
    if constexpr (MODE >= 1) {
#pragma unroll
      for (int rt = 0; rt < 2; ++rt) {
        bfrag8 A0 = *(const bfrag8*)&a1s[wv * 2304 + (rt * 16 + l15) * 72 + lg * 8];
        bfrag8 A1 = *(const bfrag8*)&a1s[wv * 2304 + (rt * 16 + l15) * 72 + 32 + lg * 8];
        f32x4 acc2[6];
#pragma unroll
        for (int f = 0; f < 6; ++f) {
          f32x4 acc = {0.f, 0.f, 0.f, 0.f};
          acc = __builtin_amdgcn_mfma_f32_16x16x32_bf16(A0, B2[f][0], acc, 0, 0, 0);
          acc = __builtin_amdgcn_mfma_f32_16x16x32_bf16(A1, B2[f][1], acc, 0, 0, 0);
          acc2[f] = acc;
        }
        if constexpr (MODE == 1) {
#pragma unroll
          for (int f = 0; f < 6; ++f)
#pragma unroll
            for (int r = 0; r < 4; ++r) { float h = acc2[f][r]; ssum[f] += h; ssq[f] += h * h; }
        } else {
          f32x4 lp = {0.f, 0.f, 0.f, 0.f};
#pragma unroll
          for (int f = 0; f < 6; ++f)
#pragma unroll
            for (int r = 0; r < 4; ++r) {
              float h = acc2[f][r] * c2[f].x + c2[f].y;
              h = fmaxf(h, 0.2f * h);
              lp[r] += h * w3v[f];
            }
#pragma unroll
          for (int m = 1; m < 16; m <<= 1) {
            lp[0] += __shfl_xor(lp[0], m);
            lp[1] += __shfl_xor(lp[1], m);
            lp[2] += __shfl_xor(lp[2], m);
            lp[3] += __shfl_xor(lp[3], m);
          }
          if (l15 == 0) {
            const int q0 = Qb + rt * 16 + lg * 4;
            *(f32x4*)&logits[(size_t)k * 65536 + (size_t)pglob * 256 + q0] = lp;
            if (a != b) {
#pragma unroll
              for (int r = 0; r < 4; ++r)
                logits[(size_t)k * 65536 + (size_t)(q0 + r) * 256 + pglob] = lp[r];
            }
          }
        }
      }
    }
  }

  if constexpr (MODE <= 1) {
#pragma unroll
    for (int f = 0; f < NF; ++f) {
      ssum[f] += __shfl_xor(ssum[f], 16); ssum[f] += __shfl_xor(ssum[f], 32);
      ssq[f]  += __shfl_xor(ssq[f], 16);  ssq[f]  += __shfl_xor(ssq[f], 32);
    }
    __syncthreads();
    if (tid < 2 * 16 * NF) sred[tid] = 0.f;
    __syncthreads();
    if (lg == 0) {
#pragma unroll
      for (int f = 0; f < NF; ++f) {
        atomicAdd(&sred[(16 * f + l15) * 2 + 0], ssum[f] * w);
        atomicAdd(&sred[(16 * f + l15) * 2 + 1], ssq[f] * w);
      }
    }
    __syncthreads();
    float* gs = (MODE == 0) ? stats1 : stats2;
    if (tid < 2 * 16 * NF) atomicAdd(&gs[k * (2 * 16 * NF) + tid], sred[tid]);
  }
}

// ------------------------- BN coefficient kernel ----------------------------
__global__ void k_bnco(const float* __restrict__ stats,
                       const float* __restrict__ g,
                       const float* __restrict__ b,
                       float2* __restrict__ coef, int nch) {
  int i = blockIdx.x * 256 + threadIdx.x;
  if (i >= 16 * nch) return;
  float sum = stats[i * 2], sq = stats[i * 2 + 1];
  const float invN = 1.f / 65536.f;
  float mean = sum * invN;
  float var = sq * invN - mean * mean;
  float s = g[i] * rsqrtf(fmaxf(var, 0.f) + 1e-5f);
  coef[i] = make_float2(s, b[i] - mean * s);
}

// --------------------- softmax + adj@xi + GCN + BN3 stats -------------------
__global__ __launch_bounds__(256) void k_graph(
    const float* __restrict__ xi,
    const float* __restrict__ logits,
    const float* __restrict__ weff,
    float* __restrict__ hi,
    float* __restrict__ stats3) {
  const int k  = blockIdx.y;
  const int pc = blockIdx.x;   // 0..7, 32 rows each
  const int tid = threadIdx.x;
  __shared__ unsigned short xis[256 * 36];   // bf16 xi, pad 36
  __shared__ float es[32][258];
  __shared__ float axs[32][33];
  __shared__ float inv_s[32];
  __shared__ float s3[64];

  const float* xik = xi + (size_t)k * 8192;
  for (int i = tid; i < 8192; i += 256) {
    int r = i >> 5, c = i & 31;
    xis[r * 36 + c] = f2bf(xik[i]);
  }
  if (tid < 64) s3[tid] = 0.f;
  __syncthreads();

  const int row = tid >> 3;    // 0..31
  const int s   = tid & 7;
  const int pglob = pc * 32 + row;
  const float* lrow = logits + (size_t)k * 65536 + (size_t)pglob * 256;

  float m = -1e30f;
  for (int q = s; q < 256; q += 8) {
    float v = lrow[q];
    m = (q == pglob) ? m : fmaxf(m, v);
  }
  m = fmaxf(m, __shfl_xor(m, 1));
  m = fmaxf(m, __shfl_xor(m, 2));
  m = fmaxf(m, __shfl_xor(m, 4));
  float sum = 0.f;
  for (int q = s; q < 256; q += 8) {
    float e = (q == pglob) ? 0.f : __expf(lrow[q] - m);
    es[row][q] = e;
    sum += e;
  }
  sum += __shfl_xor(sum, 1);
  sum += __shfl_xor(sum, 2);
  sum += __shfl_xor(sum, 4);
  if (s == 0) inv_s[row] = 1.f / sum;
  __syncthreads();

  const int c0 = s * 4;
  float a0 = 0.f, a1 = 0.f, a2 = 0.f, a3 = 0.f;
  for (int q = 0; q < 256; ++q) {
    float e = es[row][q];
    const unsigned short* xr = &xis[q * 36 + c0];
    a0 += e * bf2f(xr[0]);
    a1 += e * bf2f(xr[1]);
    a2 += e * bf2f(xr[2]);
    a3 += e * bf2f(xr[3]);
  }
  float iv = inv_s[row];
  axs[row][c0 + 0] = a0 * iv; axs[row][c0 + 1] = a1 * iv;
  axs[row][c0 + 2] = a2 * iv; axs[row][c0 + 3] = a3 * iv;
  __syncthreads();

  const float* wk = weff + (size_t)k * 2048;
  float h[4] = {0.f, 0.f, 0.f, 0.f};
  for (int u = 0; u < 32; ++u) {
    float xu = bf2f(xis[pglob * 36 + u]);
    float au = axs[row][u];
    const float* w0 = wk + u * 32 + c0;
    const float* w1 = wk + (32 + u) * 32 + c0;
#pragma unroll
    for (int j = 0; j < 4; ++j) h[j] += xu * w0[j] + au * w1[j];
  }
  float* hrow = hi + (size_t)k * 8192 + (size_t)pglob * 32 + c0;
  float vs[4], vq[4];
#pragma unroll
  for (int j = 0; j < 4; ++j) {
    float v = fmaxf(h[j], 0.2f * h[j]);
    hrow[j] = v;
    vs[j] = v; vq[j] = v * v;
  }
#pragma unroll
  for (int j = 0; j < 4; ++j) {
#pragma unroll
    for (int mm = 8; mm < 64; mm <<= 1) {
      vs[j] += __shfl_xor(vs[j], mm);
      vq[j] += __shfl_xor(vq[j], mm);
    }
  }
  if ((tid & 56) == 0) {
#pragma unroll
    for (int j = 0; j < 4; ++j) {
      atomicAdd(&s3[(c0 + j) * 2 + 0], vs[j]);
      atomicAdd(&s3[(c0 + j) * 2 + 1], vq[j]);
    }
  }
  __syncthreads();
  if (tid < 64) atomicAdd(&stats3[k * 64 + tid], s3[tid]);
}

// ------------------------------ BN3 + scatter -------------------------------
__global__ __launch_bounds__(256) void k_bn3(
    const float* __restrict__ hi, const float* __restrict__ stats3,
    const float* __restrict__ g3, const float* __restrict__ b3,
    const int* __restrict__ order, float* __restrict__ xnew) {
  int idx = blockIdx.x * 256 + threadIdx.x;   // 131072
  int k = idx >> 13, r = (idx >> 5) & 255, c = idx & 31;
  float sum = stats3[k * 64 + c * 2], sq = stats3[k * 64 + c * 2 + 1];
  const float invN = 1.f / 256.f;
  float mean = sum * invN;
  float var = sq * invN - mean * mean;
  float s = g3[k * 32 + c] * rsqrtf(fmaxf(var, 0.f) + 1e-5f);
  float t = b3[k * 32 + c] - mean * s;
  xnew[(size_t)order[k * 256 + r] * 32 + c] = hi[idx] * s + t;
}

// ------------------------------- final add ----------------------------------
__global__ __launch_bounds__(256) void k_final(const float* __restrict__ xc,
                                               const float* __restrict__ xnew,
                                               float* __restrict__ out) {
  int idx = blockIdx.x * 256 + threadIdx.x;   // 2097152 float4 groups
  int c4 = idx & 7, v = idx >> 3;
  int z = v & 63, y = (v >> 6) & 63, x = v >> 12;
  int sx = (x >> 2) + (x & 3) - 1;
  int sy = (y >> 2) + (y & 3) - 1;
  int sz = (z >> 2) + (z & 3) - 1;
  f32x4 add = {0.f, 0.f, 0.f, 0.f};
  if ((unsigned)sx < 16u && (unsigned)sy < 16u && (unsigned)sz < 16u)
    add = *(const f32x4*)&xnew[(size_t)(((sx << 4) + sy) * 16 + sz) * 32 + c4 * 4];
  const f32x4 a = *(const f32x4*)&xc[(size_t)idx * 4];
  *(f32x4*)&out[(size_t)idx * 4] = a + add;
}

// ----------------------------------------------------------------------------
extern "C" void kernel_launch(void* const* d_in, const int* in_sizes, int n_in,
                              void* d_out, int out_size, void* d_ws, size_t ws_size,
                              hipStream_t stream) {
  const float* xc   = (const float*)d_in[0];
  const int*   ci   = (const int*)  d_in[1];
  const float* c1w  = (const float*)d_in[2];
  const float* bn1g = (const float*)d_in[4];
  const float* bn1b = (const float*)d_in[5];
  const float* c2w  = (const float*)d_in[6];
  const float* bn2g = (const float*)d_in[8];
  const float* bn2b = (const float*)d_in[9];
  const float* c3w  = (const float*)d_in[10];
  const float* gcnw = (const float*)d_in[12];
  const float* bn3g = (const float*)d_in[13];
  const float* bn3b = (const float*)d_in[14];
  const float* mw1  = (const float*)d_in[15];
  const float* mb1  = (const float*)d_in[16];
  const float* mw2  = (const float*)d_in[17];
  const float* mb2  = (const float*)d_in[18];
  const float* mw3  = (const float*)d_in[19];
  const float* mb3  = (const float*)d_in[20];

  float* wsf = (float*)d_ws;
  float*  x      = wsf + 0;          // 131072 (dead after k_order; reused below)
  float*  xi     = wsf + 131072;     // 131072
  float*  xnew   = wsf + 262144;     // 131072
  float*  hi     = wsf + 393216;     // 131072
  float*  weff   = wsf + 524288;     // 32768
  float*  stats1 = wsf + 557056;     // 2048
  float*  stats2 = wsf + 559104;     // 3072
  float*  stats3 = wsf + 562176;     // 1024
  float2* coef1  = (float2*)(wsf + 563200);  // 2048 floats
  float2* coef2  = (float2*)(wsf + 565248);  // 3072 floats
  float*  logits = wsf + 568320;     // 1048576
  unsigned char* wsb = (unsigned char*)d_ws;
  int* order = (int*)(wsb + 6467584);
  unsigned short* w1b = (unsigned short*)(wsb + 6467584 + 16384);
  unsigned short* w2b = (unsigned short*)(wsb + 6467584 + 16384 + 65536);
  // MLP scratch aliases the dead x region (x consumed by k_order before k_mlp1)
  float* h2mlp = x;                  // 4096 floats
  float* swb   = x + 4096;           // 16384 floats

  hipMemsetAsync(stats1, 0, 6144 * sizeof(float), stream);  // stats1|2|3
  k_pool <<<512, 256, 0, stream>>>(xc, x);
  k_wcvt <<<384, 256, 0, stream>>>(c1w, c2w, w1b, w2b);
  k_order<<<16, 256, 0, stream>>>(ci, x, order, xi);
  k_mlp1 <<<16, 256, 0, stream>>>(xi, mw1, mb1, mw2, mb2, h2mlp);
  k_mlp2 <<<dim3(4, 16), 256, 0, stream>>>(h2mlp, mw3, mb3, swb);
  k_mlp3 <<<dim3(8, 16), 256, 0, stream>>>(swb, gcnw, weff);
  dim3 gconv(36, 16);
  k_conv<0><<<gconv, 256, 0, stream>>>(xi, w1b, w2b, coef1, coef2, c3w, stats1, stats2, logits);
  k_bnco <<<4, 256, 0, stream>>>(stats1, bn1g, bn1b, coef1, 64);
  k_conv<1><<<gconv, 256, 0, stream>>>(xi, w1b, w2b, coef1, coef2, c3w, stats1, stats2, logits);
  k_bnco <<<6, 256, 0, stream>>>(stats2, bn2g, bn2b, coef2, 96);
  k_conv<2><<<gconv, 256, 0, stream>>>(xi, w1b, w2b, coef1, coef2, c3w, stats1, stats2, logits);
  k_graph<<<dim3(8, 16), 256, 0, stream>>>(xi, logits, weff, hi, stats3);
  k_bn3  <<<512, 256, 0, stream>>>(hi, stats3, bn3g, bn3b, order, xnew);
  k_final<<<8192, 256, 0, stream>>>(xc, xnew, (float*)d_out);
}